// Round 1
// baseline (165.159 us; speedup 1.0000x reference)
//
#include <hip/hip_runtime.h>
#include <math.h>

#define DI __device__ __forceinline__

// Problem constants
constexpr int B_ = 2, N_ = 512, T_ = 12, T2_ = 6, H_ = 8, E_ = 128, D_ = 16, TH_ = 16;
constexpr int QS_ = 4;  // q-split slots for colsum partials
constexpr float MARKOFF_ = -100000000.0f;
constexpr float INVSCALE_ = 0.088388347648318447f;  // 1/sqrt(128)

// Workspace layout (float offsets)
constexpr size_t PSZ_ = (size_t)B_ * T2_ * N_ * TH_ * D_;  // 1,572,864
constexpr size_t PV_OFF_ = 0;
constexpr size_t PK_OFF_ = PSZ_;
constexpr size_t PQ_OFF_ = 2 * PSZ_;
constexpr size_t CS_OFF_ = 3 * PSZ_;
constexpr size_t CS_SZ_ = (size_t)B_ * T2_ * QS_ * N_ * TH_;  // 393,216
constexpr size_t OH_OFF_ = CS_OFF_ + CS_SZ_;
constexpr size_t OH_SLOT_ = (size_t)B_ * N_ * T_ * E_;  // 1,572,864

DI void load16(float* dst, const float* src) {
  #pragma unroll
  for (int c = 0; c < 4; ++c) {
    float4 v = reinterpret_cast<const float4*>(src)[c];
    dst[c * 4 + 0] = v.x; dst[c * 4 + 1] = v.y;
    dst[c * 4 + 2] = v.z; dst[c * 4 + 3] = v.w;
  }
}

DI float dot16(const float* a, const float* b) {
  float s = 0.f;
  #pragma unroll
  for (int i = 0; i < 16; ++i) s = fmaf(a[i], b[i], s);
  return s;
}

// ---------------- Kernel 1: QKV head projection ----------------
// One thread per (b,n,t,h). Out layout: P[b][t2][n][th][d], th = (t&1)*8+h.
__global__ __launch_bounds__(256) void k_proj(
    const float* __restrict__ vals, const float* __restrict__ keys,
    const float* __restrict__ qry,
    const float* __restrict__ Wv, const float* __restrict__ Wk,
    const float* __restrict__ Wq,
    float* __restrict__ Pv, float* __restrict__ Pk, float* __restrict__ Pq) {
  int gid = blockIdx.x * 256 + threadIdx.x;  // 0 .. 98303
  int h = gid & 7;
  int t = (gid >> 3) % 12;
  int n = (gid / 96) & 511;
  int b = gid / (96 * 512);
  size_t ioff = ((size_t)(b * 512 + n) * 12 + t) * 128 + h * 16;
  int t2 = t >> 1, th = ((t & 1) << 3) | h;
  size_t ooff = (((size_t)(b * 6 + t2) * 512 + n) * 16 + th) * 16;

  const float* ins[3] = {vals, keys, qry};
  const float* wm[3] = {Wv, Wk, Wq};
  float* outs[3] = {Pv, Pk, Pq};
  #pragma unroll
  for (int s = 0; s < 3; ++s) {
    float x[16];
    load16(x, ins[s] + ioff);
    const float* W = wm[s];
    float4* op = reinterpret_cast<float4*>(outs[s] + ooff);
    #pragma unroll
    for (int c = 0; c < 4; ++c) {
      float r4[4];
      #pragma unroll
      for (int ii = 0; ii < 4; ++ii) {
        int i = c * 4 + ii;
        float a = 0.f;
        #pragma unroll
        for (int j = 0; j < 16; ++j) a = fmaf(W[i * 16 + j], x[j], a);
        r4[ii] = a;
      }
      op[c] = make_float4(r4[0], r4[1], r4[2], r4[3]);
    }
  }
}

// ---------------- Kernel 2: column-sum of exp (softmax denominator) ------
// grid = B*T2*16*QS. Block: 32 k-columns (2 per thread), 128 q rows (q-split).
__global__ __launch_bounds__(256) void k_colsum(
    const float* __restrict__ Pq, const float* __restrict__ Pk,
    const float* __restrict__ mask, float* __restrict__ cs) {
  __shared__ float qlds[32 * 320];   // 32 q rows, padded stride 20 per th
  __shared__ float mlds[32 * 32];    // mask tile [q][k_local]
  int blk = blockIdx.x;
  int qs = blk & 3;
  int kt = (blk >> 2) & 15;
  int r = blk >> 6;  // 0..11
  int t2 = r % 6, b = r / 6;
  int tid = threadIdx.x;
  int th = tid & 15, ks = tid >> 4;  // ks 0..15
  int kA = kt * 32 + ks, kB = kA + 16;

  const float* slab_k = Pk + (size_t)(b * 6 + t2) * 512 * 256;
  const float* slab_q = Pq + (size_t)(b * 6 + t2) * 512 * 256;
  float ka[16], kb[16];
  load16(ka, slab_k + ((size_t)kA * 16 + th) * 16);
  load16(kb, slab_k + ((size_t)kB * 16 + th) * 16);

  float sA = 0.f, sB = 0.f;
  for (int qc = 0; qc < 4; ++qc) {
    int q0 = qs * 128 + qc * 32;
    const float4* src = reinterpret_cast<const float4*>(slab_q + (size_t)q0 * 256);
    #pragma unroll
    for (int rr = 0; rr < 8; ++rr) {
      int f4 = tid + rr * 256;
      float4 v = src[f4];
      int fl = f4 << 2;
      int qq = fl >> 8, c = fl & 255;
      *reinterpret_cast<float4*>(&qlds[qq * 320 + (c >> 4) * 20 + (c & 15)]) = v;
    }
    // mask tile: 32q x 32k
    #pragma unroll
    for (int rr = 0; rr < 4; ++rr) {
      int idx = tid + rr * 256;
      int mq = idx >> 5, mk = idx & 31;
      mlds[idx] = mask[(size_t)(q0 + mq) * 512 + kt * 32 + mk];
    }
    __syncthreads();
    #pragma unroll 2
    for (int qq = 0; qq < 32; ++qq) {
      float qv[16];
      load16(qv, &qlds[qq * 320 + th * 20]);
      float mA = mlds[qq * 32 + ks];
      float mB = mlds[qq * 32 + ks + 16];
      float eA = dot16(qv, ka), eB = dot16(qv, kb);
      float xA = fminf(fmaxf((eA * mA + MARKOFF_ * (1.f - mA)) * INVSCALE_, -5.f), 5.f);
      float xB = fminf(fmaxf((eB * mB + MARKOFF_ * (1.f - mB)) * INVSCALE_, -5.f), 5.f);
      sA += __expf(xA);
      sB += __expf(xB);
    }
    __syncthreads();
  }
  size_t cbase = ((size_t)(b * 6 + t2) * 4 + qs) * 8192;
  cs[cbase + kA * 16 + th] = sA;
  cs[cbase + kB * 16 + th] = sB;
}

// ---------------- Kernel 3: attention write + A@V accumulate ----------------
// grid = B*T2*16*KS. Block: 32 q rows (2/thread), k-range 512/KS, all 16 th.
__global__ __launch_bounds__(256) void k_attn(
    const float* __restrict__ Pq, const float* __restrict__ Pk,
    const float* __restrict__ Pv, const float* __restrict__ mask,
    const float* __restrict__ cs, float* __restrict__ Aout,
    float* __restrict__ Oh, int KS) {
  __shared__ float klds[16 * 320];
  __shared__ float vlds[16 * 320];
  __shared__ float ilds[256];
  __shared__ float mlds[32 * 16];  // mask tile [q_local][k_local]
  int blk = blockIdx.x;
  int ksp = blk % KS;
  int rest = blk / KS;
  int qt = rest & 15;
  int r = rest >> 4;  // 0..11
  int t2 = r % 6, b = r / 6;
  int tid = threadIdx.x;
  int th = tid & 15, qsl = tid >> 4;
  int qA = qt * 32 + qsl, qB = qA + 16;

  const float* slab_q = Pq + (size_t)(b * 6 + t2) * 512 * 256;
  const float* slab_k = Pk + (size_t)(b * 6 + t2) * 512 * 256;
  const float* slab_v = Pv + (size_t)(b * 6 + t2) * 512 * 256;
  float qa[16], qb[16];
  load16(qa, slab_q + ((size_t)qA * 16 + th) * 16);
  load16(qb, slab_q + ((size_t)qB * 16 + th) * 16);
  float accA[16], accB[16];
  #pragma unroll
  for (int i = 0; i < 16; ++i) { accA[i] = 0.f; accB[i] = 0.f; }

  int kcount = 512 / KS;
  int kbase = ksp * kcount;
  const float* cbase = cs + ((size_t)(b * 6 + t2) * 4) * 8192;

  for (int kt = 0; kt < kcount / 16; ++kt) {
    int k0 = kbase + kt * 16;
    const float4* ksrc = reinterpret_cast<const float4*>(slab_k + (size_t)k0 * 256);
    const float4* vsrc = reinterpret_cast<const float4*>(slab_v + (size_t)k0 * 256);
    #pragma unroll
    for (int rr = 0; rr < 4; ++rr) {
      int f4 = tid + rr * 256;
      int fl = f4 << 2;
      int kk = fl >> 8, c = fl & 255;
      int dst = kk * 320 + (c >> 4) * 20 + (c & 15);
      *reinterpret_cast<float4*>(&klds[dst]) = ksrc[f4];
      *reinterpret_cast<float4*>(&vlds[dst]) = vsrc[f4];
    }
    {  // softmax denominators -> reciprocals
      int kl = tid >> 4, thv = tid & 15;
      const float* cp = cbase + (size_t)(k0 + kl) * 16 + thv;
      float s = cp[0] + cp[8192] + cp[16384] + cp[24576];
      ilds[kl * 16 + thv] = 1.0f / s;
    }
    {  // mask tile 32q x 16k
      int rr = tid;                       // 512 entries, 2 per thread
      int mq0 = rr >> 4, mk0 = rr & 15;
      mlds[rr] = mask[(size_t)(qt * 32 + mq0) * 512 + k0 + mk0];
      int rr1 = tid + 256;
      int mq1 = rr1 >> 4, mk1 = rr1 & 15;
      mlds[rr1] = mask[(size_t)(qt * 32 + mq1) * 512 + k0 + mk1];
    }
    __syncthreads();
    for (int kk = 0; kk < 16; ++kk) {
      int k = k0 + kk;
      float kv[16], vv[16];
      load16(kv, &klds[kk * 320 + th * 20]);
      float inv = ilds[kk * 16 + th];
      float mA = mlds[qsl * 16 + kk];
      float mB = mlds[(qsl + 16) * 16 + kk];
      float eA = dot16(qa, kv), eB = dot16(qb, kv);
      float xA = fminf(fmaxf((eA * mA + MARKOFF_ * (1.f - mA)) * INVSCALE_, -5.f), 5.f);
      float xB = fminf(fmaxf((eB * mB + MARKOFF_ * (1.f - mB)) * INVSCALE_, -5.f), 5.f);
      float aA = __expf(xA) * inv;
      float aB = __expf(xB) * inv;
      __builtin_nontemporal_store(aA, &Aout[((size_t)(b * 512 + qA) * 512 + k) * 96 + t2 * 16 + th]);
      __builtin_nontemporal_store(aB, &Aout[((size_t)(b * 512 + qB) * 512 + k) * 96 + t2 * 16 + th]);
      load16(vv, &vlds[kk * 320 + th * 20]);
      #pragma unroll
      for (int d2 = 0; d2 < 16; ++d2) {
        accA[d2] = fmaf(aA, vv[d2], accA[d2]);
        accB[d2] = fmaf(aB, vv[d2], accB[d2]);
      }
    }
    __syncthreads();
  }
  int t = 2 * t2 + (th >> 3), h = th & 7;
  float* oA = Oh + (((size_t)(ksp * 2 + b) * 512 + qA) * 12 + t) * 128 + h * 16;
  float* oB = Oh + (((size_t)(ksp * 2 + b) * 512 + qB) * 12 + t) * 128 + h * 16;
  #pragma unroll
  for (int c = 0; c < 4; ++c) {
    reinterpret_cast<float4*>(oA)[c] =
        make_float4(accA[c * 4], accA[c * 4 + 1], accA[c * 4 + 2], accA[c * 4 + 3]);
    reinterpret_cast<float4*>(oB)[c] =
        make_float4(accB[c * 4], accB[c * 4 + 1], accB[c * 4 + 2], accB[c * 4 + 3]);
  }
}

// ---------------- Kernel 4: output projection out = Oh @ Wo^T + bo ---------
// grid = B*N blocks, 128 threads; each block does the 12 t-rows of one (b,n).
__global__ __launch_bounds__(128) void k_outproj(
    const float* __restrict__ Oh, const float* __restrict__ Wo,
    const float* __restrict__ bo, float* __restrict__ out, int KS) {
  __shared__ float xr[12 * 128];
  int bn = blockIdx.x;
  int b = bn >> 9, n = bn & 511;
  int col = threadIdx.x;
  for (int i = col; i < 1536; i += 128) {
    float s = 0.f;
    for (int sl = 0; sl < KS; ++sl)
      s += Oh[((size_t)(sl * 2 + b) * 512 + n) * 1536 + i];
    xr[i] = s;
  }
  __syncthreads();
  float acc[12];
  float bias = bo[col];
  #pragma unroll
  for (int rr = 0; rr < 12; ++rr) acc[rr] = bias;
  const float4* wrow = reinterpret_cast<const float4*>(Wo + (size_t)col * 128);
  #pragma unroll 8
  for (int jc = 0; jc < 32; ++jc) {
    float4 w = wrow[jc];
    #pragma unroll
    for (int rr = 0; rr < 12; ++rr) {
      const float* x = &xr[rr * 128 + jc * 4];
      acc[rr] = fmaf(w.x, x[0], fmaf(w.y, x[1], fmaf(w.z, x[2], fmaf(w.w, x[3], acc[rr]))));
    }
  }
  size_t obase = ((size_t)(b * 512 + n)) * 1536;
  #pragma unroll
  for (int rr = 0; rr < 12; ++rr) out[obase + rr * 128 + col] = acc[rr];
}

extern "C" void kernel_launch(void* const* d_in, const int* in_sizes, int n_in,
                              void* d_out, int out_size, void* d_ws, size_t ws_size,
                              hipStream_t stream) {
  (void)in_sizes; (void)n_in; (void)out_size;
  const float* vals = (const float*)d_in[0];
  const float* keys = (const float*)d_in[1];
  const float* qry  = (const float*)d_in[2];
  const float* mask = (const float*)d_in[3];
  const float* Wv = (const float*)d_in[4];
  const float* Wk = (const float*)d_in[5];
  const float* Wq = (const float*)d_in[6];
  const float* Wo = (const float*)d_in[7];
  const float* bo = (const float*)d_in[8];
  float* out = (float*)d_out;
  float* Aout = out + (size_t)B_ * N_ * T_ * E_;  // attention starts after `out`
  float* ws = (float*)d_ws;
  float* Pv = ws + PV_OFF_;
  float* Pk = ws + PK_OFF_;
  float* Pq = ws + PQ_OFF_;
  float* cs = ws + CS_OFF_;
  float* Oh = ws + OH_OFF_;

  // Pick k-split by available workspace (4 preferred for occupancy).
  int KS = 4;
  if (ws_size < (OH_OFF_ + 4 * OH_SLOT_) * sizeof(float)) {
    KS = (ws_size >= (OH_OFF_ + 2 * OH_SLOT_) * sizeof(float)) ? 2 : 1;
  }

  k_proj<<<384, 256, 0, stream>>>(vals, keys, qry, Wv, Wk, Wq, Pv, Pk, Pq);
  k_colsum<<<768, 256, 0, stream>>>(Pq, Pk, mask, cs);
  k_attn<<<192 * KS, 256, 0, stream>>>(Pq, Pk, Pv, mask, cs, Aout, Oh, KS);
  k_outproj<<<1024, 128, 0, stream>>>(Oh, Wo, bo, out, KS);
}